// Round 3
// baseline (43.721 us; speedup 1.0000x reference)
//
#include <hip/hip_runtime.h>

#define D_MODEL 2048
#define EPS 1e-5f

typedef float f32x4 __attribute__((ext_vector_type(4)));

// One WAVE (64 lanes) per row. Lane l handles 8 float4 chunks:
// f32x4 at element offset (c*256 + l*4) for c in 0..7 -> each chunk is a
// fully-coalesced 1KiB wave access. No LDS, no __syncthreads: waves in a
// block proceed independently, so there is no barrier convoy.
__global__ __launch_bounds__(256) void rmsnorm_kernel(
    const float* __restrict__ x,
    const float* __restrict__ gain,
    float* __restrict__ out)
{
    const int wave_in_block = threadIdx.x >> 6;
    const int lane = threadIdx.x & 63;
    const size_t row = (size_t)blockIdx.x * 4 + wave_in_block;

    const float* __restrict__ xr = x + row * (size_t)D_MODEL;
    float* __restrict__ orow = out + row * (size_t)D_MODEL;

    f32x4 v[8];
    #pragma unroll
    for (int c = 0; c < 8; ++c)
        v[c] = *reinterpret_cast<const f32x4*>(xr + c * 256 + lane * 4);

    float ss = 0.0f;
    #pragma unroll
    for (int c = 0; c < 8; ++c)
        ss += v[c].x * v[c].x + v[c].y * v[c].y + v[c].z * v[c].z + v[c].w * v[c].w;

    // 64-lane butterfly reduction, wave-local only
    #pragma unroll
    for (int off = 32; off > 0; off >>= 1)
        ss += __shfl_xor(ss, off, 64);

    const float scale = rsqrtf(ss * (1.0f / (float)D_MODEL) + EPS);

    #pragma unroll
    for (int c = 0; c < 8; ++c) {
        const f32x4 g = *reinterpret_cast<const f32x4*>(gain + c * 256 + lane * 4);
        f32x4 o;
        o.x = v[c].x * scale * g.x;
        o.y = v[c].y * scale * g.y;
        o.z = v[c].z * scale * g.z;
        o.w = v[c].w * scale * g.w;
        __builtin_nontemporal_store(o, reinterpret_cast<f32x4*>(orow + c * 256 + lane * 4));
    }
}

extern "C" void kernel_launch(void* const* d_in, const int* in_sizes, int n_in,
                              void* d_out, int out_size, void* d_ws, size_t ws_size,
                              hipStream_t stream) {
    const float* x = (const float*)d_in[0];
    const float* gain = (const float*)d_in[1];
    float* out = (float*)d_out;

    const int rows = in_sizes[0] / D_MODEL;  // 16384
    rmsnorm_kernel<<<rows / 4, 256, 0, stream>>>(x, gain, out);
}